// Round 1
// baseline (258.452 us; speedup 1.0000x reference)
//
#include <hip/hip_runtime.h>
#include <math.h>

#define NODE_DIM 128
#define EDGE_DIM 128
#define N_RADIAL 16

// ---------------------------------------------------------------------------
// Precompute: t1[r][d] = sum_k embed[r][k] * edge_w[k][d]        + edge_b[d]
//             t2[r][d] = sum_k embed[r][k] * edge_w[128+k][d]
// One block per table row r, 128 threads (one per output d).
// ---------------------------------------------------------------------------
__global__ void precompute_node_tables(const float* __restrict__ embed_table,
                                       const float* __restrict__ edge_w,
                                       const float* __restrict__ edge_b,
                                       float* __restrict__ t1,
                                       float* __restrict__ t2) {
    const int r = blockIdx.x;
    const int d = threadIdx.x;
    float s1 = edge_b[d];
    float s2 = 0.0f;
    const float* er = embed_table + (long)r * NODE_DIM;
#pragma unroll 8
    for (int k = 0; k < NODE_DIM; ++k) {
        const float e = er[k];
        s1 += e * edge_w[(long)k * EDGE_DIM + d];                // W_j block
        s2 += e * edge_w[(long)(NODE_DIM + k) * EDGE_DIM + d];   // W_i block
    }
    t1[(long)r * EDGE_DIM + d] = s1;
    t2[(long)r * EDGE_DIM + d] = s2;
}

// ---------------------------------------------------------------------------
// Precompute: w3c[r][d] = sum_k rbf_w[r][k] * edge_w[256+k][d]   (16 x 128)
// ---------------------------------------------------------------------------
__global__ void precompute_rbf_mat(const float* __restrict__ rbf_w,
                                   const float* __restrict__ edge_w,
                                   float* __restrict__ w3c) {
    const int r = blockIdx.x;   // 0..15
    const int d = threadIdx.x;  // 0..127
    float s = 0.0f;
    const float* rr = rbf_w + (long)r * EDGE_DIM;
#pragma unroll 8
    for (int k = 0; k < EDGE_DIM; ++k)
        s += rr[k] * edge_w[(long)(2 * NODE_DIM + k) * EDGE_DIM + d];
    w3c[(long)r * EDGE_DIM + d] = s;
}

// ---------------------------------------------------------------------------
// Main kernel: 32 lanes per edge, each lane computes one float4 of the
// 128-wide output row.  h = t1[z[idx_j]] + t2[z[idx_i]] + rbf[e] @ w3c
// out = h * sigmoid(h)
// ---------------------------------------------------------------------------
__global__ void __launch_bounds__(256) edge_embed_kernel(
        const int*   __restrict__ z,
        const float* __restrict__ rbf,
        const int*   __restrict__ idx_i,
        const int*   __restrict__ idx_j,
        const float* __restrict__ t1,
        const float* __restrict__ t2,
        const float* __restrict__ w3c,
        float* __restrict__ out,
        int n_edges) {
    const int sub = threadIdx.x & 31;           // which float4 of the row
    // Hoist this lane's 16x4 slice of w3c into registers (constant over loop).
    float4 w[N_RADIAL];
#pragma unroll
    for (int r = 0; r < N_RADIAL; ++r)
        w[r] = *reinterpret_cast<const float4*>(&w3c[r * EDGE_DIM + sub * 4]);

    const int total  = n_edges * 32;            // 25.6M, fits in int
    const int stride = gridDim.x * blockDim.x;  // multiple of 32
    for (int gid = blockIdx.x * blockDim.x + threadIdx.x; gid < total;
         gid += stride) {
        const int e  = gid >> 5;
        const int zj = z[idx_j[e]];
        const int zi = z[idx_i[e]];

        float4 acc = *reinterpret_cast<const float4*>(
            &t1[(long)zj * EDGE_DIM + sub * 4]);
        const float4 a2 = *reinterpret_cast<const float4*>(
            &t2[(long)zi * EDGE_DIM + sub * 4]);
        acc.x += a2.x; acc.y += a2.y; acc.z += a2.z; acc.w += a2.w;

        const float4* rb = reinterpret_cast<const float4*>(&rbf[(long)e * N_RADIAL]);
#pragma unroll
        for (int q = 0; q < 4; ++q) {
            const float4 rv = rb[q];
            acc.x += rv.x * w[q * 4 + 0].x;
            acc.y += rv.x * w[q * 4 + 0].y;
            acc.z += rv.x * w[q * 4 + 0].z;
            acc.w += rv.x * w[q * 4 + 0].w;

            acc.x += rv.y * w[q * 4 + 1].x;
            acc.y += rv.y * w[q * 4 + 1].y;
            acc.z += rv.y * w[q * 4 + 1].z;
            acc.w += rv.y * w[q * 4 + 1].w;

            acc.x += rv.z * w[q * 4 + 2].x;
            acc.y += rv.z * w[q * 4 + 2].y;
            acc.z += rv.z * w[q * 4 + 2].z;
            acc.w += rv.z * w[q * 4 + 2].w;

            acc.x += rv.w * w[q * 4 + 3].x;
            acc.y += rv.w * w[q * 4 + 3].y;
            acc.z += rv.w * w[q * 4 + 3].z;
            acc.w += rv.w * w[q * 4 + 3].w;
        }

        // swish: h * sigmoid(h)
        float4 o;
        o.x = acc.x / (1.0f + __expf(-acc.x));
        o.y = acc.y / (1.0f + __expf(-acc.y));
        o.z = acc.z / (1.0f + __expf(-acc.z));
        o.w = acc.w / (1.0f + __expf(-acc.w));

        *reinterpret_cast<float4*>(&out[(long)e * EDGE_DIM + sub * 4]) = o;
    }
}

extern "C" void kernel_launch(void* const* d_in, const int* in_sizes, int n_in,
                              void* d_out, int out_size, void* d_ws, size_t ws_size,
                              hipStream_t stream) {
    const int*   z           = (const int*)  d_in[0];
    const float* rbf         = (const float*)d_in[1];
    const int*   idx_i       = (const int*)  d_in[2];
    const int*   idx_j       = (const int*)  d_in[3];
    const float* embed_table = (const float*)d_in[4];
    const float* rbf_w       = (const float*)d_in[5];
    const float* edge_w      = (const float*)d_in[6];
    const float* edge_b      = (const float*)d_in[7];

    const int max_z   = in_sizes[4] / NODE_DIM;   // 100
    const int n_edges = in_sizes[2];              // 800000

    float* t1  = (float*)d_ws;                         // max_z x 128
    float* t2  = t1 + (long)max_z * EDGE_DIM;          // max_z x 128
    float* w3c = t2 + (long)max_z * EDGE_DIM;          // 16 x 128
    float* out = (float*)d_out;

    precompute_node_tables<<<max_z, EDGE_DIM, 0, stream>>>(embed_table, edge_w,
                                                           edge_b, t1, t2);
    precompute_rbf_mat<<<N_RADIAL, EDGE_DIM, 0, stream>>>(rbf_w, edge_w, w3c);

    const int block = 256;
    const int total = n_edges * 32;
    int grid = (total + block - 1) / block;
    if (grid > 2048) grid = 2048;                 // grid-stride the rest
    edge_embed_kernel<<<grid, block, 0, stream>>>(z, rbf, idx_i, idx_j,
                                                  t1, t2, w3c, out, n_edges);
}

// Round 2
// 182.580 us; speedup vs baseline: 1.4156x; 1.4156x over previous
//
#include <hip/hip_runtime.h>
#include <math.h>

#define NODE_DIM 128
#define EDGE_DIM 128
#define N_RADIAL 16
#define CHUNK    64          // edges per block-iteration

// ---------------------------------------------------------------------------
// Precompute: t1[r][d] = sum_k embed[r][k] * edge_w[k][d]        + edge_b[d]
//             t2[r][d] = sum_k embed[r][k] * edge_w[128+k][d]
// ---------------------------------------------------------------------------
__global__ void precompute_node_tables(const float* __restrict__ embed_table,
                                       const float* __restrict__ edge_w,
                                       const float* __restrict__ edge_b,
                                       float* __restrict__ t1,
                                       float* __restrict__ t2) {
    const int r = blockIdx.x;
    const int d = threadIdx.x;
    float s1 = edge_b[d];
    float s2 = 0.0f;
    const float* er = embed_table + (long)r * NODE_DIM;
#pragma unroll 8
    for (int k = 0; k < NODE_DIM; ++k) {
        const float e = er[k];
        s1 += e * edge_w[(long)k * EDGE_DIM + d];
        s2 += e * edge_w[(long)(NODE_DIM + k) * EDGE_DIM + d];
    }
    t1[(long)r * EDGE_DIM + d] = s1;
    t2[(long)r * EDGE_DIM + d] = s2;
}

// ---------------------------------------------------------------------------
// Precompute: w3c[r][d] = sum_k rbf_w[r][k] * edge_w[256+k][d]   (16 x 128)
// ---------------------------------------------------------------------------
__global__ void precompute_rbf_mat(const float* __restrict__ rbf_w,
                                   const float* __restrict__ edge_w,
                                   float* __restrict__ w3c) {
    const int r = blockIdx.x;   // 0..15
    const int d = threadIdx.x;  // 0..127
    float s = 0.0f;
    const float* rr = rbf_w + (long)r * EDGE_DIM;
#pragma unroll 8
    for (int k = 0; k < EDGE_DIM; ++k)
        s += rr[k] * edge_w[(long)(2 * NODE_DIM + k) * EDGE_DIM + d];
    w3c[(long)r * EDGE_DIM + d] = s;
}

// ---------------------------------------------------------------------------
// Main kernel, block-cooperative:
//  - stage rbf[64 edges] into LDS (coalesced: 1 float4/thread)
//  - waves 0-1 resolve z[idx_j] / z[idx_i] once per edge -> LDS
//  - compute: each thread owns sub-column (tid&31), 8 edges, reading
//    zj/zi + rbf via LDS broadcast, t1/t2 rows via L1/L2, w3c in VGPRs.
// ---------------------------------------------------------------------------
__global__ void __launch_bounds__(256, 4) edge_embed_kernel(
        const int*   __restrict__ z,
        const float* __restrict__ rbf,
        const int*   __restrict__ idx_i,
        const int*   __restrict__ idx_j,
        const float* __restrict__ t1,
        const float* __restrict__ t2,
        const float* __restrict__ w3c,
        float* __restrict__ out,
        int n_edges) {
    __shared__ float s_rbf[CHUNK * N_RADIAL];   // 4 KB
    __shared__ int   s_zj[CHUNK];
    __shared__ int   s_zi[CHUNK];

    const int tid = threadIdx.x;
    const int sub = tid & 31;                   // float4 column of the row

    // Hoist this lane's 16x4 slice of w3c into registers.
    float4 w[N_RADIAL];
#pragma unroll
    for (int r = 0; r < N_RADIAL; ++r)
        w[r] = *reinterpret_cast<const float4*>(&w3c[r * EDGE_DIM + sub * 4]);

    const int nchunks = (n_edges + CHUNK - 1) / CHUNK;

    for (int chunk = blockIdx.x; chunk < nchunks; chunk += gridDim.x) {
        const int base = chunk * CHUNK;

        // ---- stage rbf: 256 float4 = 64 edges x 16 floats (coalesced) ----
        {
            const int f4 = tid;                        // 0..255
            const int gfl = base * N_RADIAL + f4 * 4;  // global float index
            if (gfl < n_edges * N_RADIAL) {
                reinterpret_cast<float4*>(s_rbf)[f4] =
                    *reinterpret_cast<const float4*>(&rbf[gfl]);
            }
        }
        // ---- resolve indices once per edge (waves 0-1) ----
        if (tid < CHUNK) {
            const int e = base + tid;
            s_zj[tid] = (e < n_edges) ? z[idx_j[e]] : 0;
        } else if (tid < 2 * CHUNK) {
            const int e = base + (tid - CHUNK);
            s_zi[tid - CHUNK] = (e < n_edges) ? z[idx_i[e]] : 0;
        }
        __syncthreads();

        // ---- compute: 8 edges per thread ----
        const int e0 = tid >> 5;                   // 0..7
#pragma unroll
        for (int s = 0; s < 8; ++s) {
            const int el = e0 + s * 8;             // 0..63
            const int e  = base + el;
            if (e >= n_edges) break;
            const int zj = s_zj[el];
            const int zi = s_zi[el];

            float4 acc = *reinterpret_cast<const float4*>(
                &t1[(long)zj * EDGE_DIM + sub * 4]);
            const float4 a2 = *reinterpret_cast<const float4*>(
                &t2[(long)zi * EDGE_DIM + sub * 4]);
            acc.x += a2.x; acc.y += a2.y; acc.z += a2.z; acc.w += a2.w;

            const float4* rb =
                reinterpret_cast<const float4*>(&s_rbf[el * N_RADIAL]);
#pragma unroll
            for (int q = 0; q < 4; ++q) {
                const float4 rv = rb[q];
                acc.x += rv.x * w[q * 4 + 0].x;
                acc.y += rv.x * w[q * 4 + 0].y;
                acc.z += rv.x * w[q * 4 + 0].z;
                acc.w += rv.x * w[q * 4 + 0].w;

                acc.x += rv.y * w[q * 4 + 1].x;
                acc.y += rv.y * w[q * 4 + 1].y;
                acc.z += rv.y * w[q * 4 + 1].z;
                acc.w += rv.y * w[q * 4 + 1].w;

                acc.x += rv.z * w[q * 4 + 2].x;
                acc.y += rv.z * w[q * 4 + 2].y;
                acc.z += rv.z * w[q * 4 + 2].z;
                acc.w += rv.z * w[q * 4 + 2].w;

                acc.x += rv.w * w[q * 4 + 3].x;
                acc.y += rv.w * w[q * 4 + 3].y;
                acc.z += rv.w * w[q * 4 + 3].z;
                acc.w += rv.w * w[q * 4 + 3].w;
            }

            float4 o;
            o.x = acc.x / (1.0f + __expf(-acc.x));
            o.y = acc.y / (1.0f + __expf(-acc.y));
            o.z = acc.z / (1.0f + __expf(-acc.z));
            o.w = acc.w / (1.0f + __expf(-acc.w));

            *reinterpret_cast<float4*>(&out[(long)e * EDGE_DIM + sub * 4]) = o;
        }
        __syncthreads();   // LDS safe to overwrite next iteration
    }
}

extern "C" void kernel_launch(void* const* d_in, const int* in_sizes, int n_in,
                              void* d_out, int out_size, void* d_ws, size_t ws_size,
                              hipStream_t stream) {
    const int*   z           = (const int*)  d_in[0];
    const float* rbf         = (const float*)d_in[1];
    const int*   idx_i       = (const int*)  d_in[2];
    const int*   idx_j       = (const int*)  d_in[3];
    const float* embed_table = (const float*)d_in[4];
    const float* rbf_w       = (const float*)d_in[5];
    const float* edge_w      = (const float*)d_in[6];
    const float* edge_b      = (const float*)d_in[7];

    const int max_z   = in_sizes[4] / NODE_DIM;   // 100
    const int n_edges = in_sizes[2];              // 800000

    float* t1  = (float*)d_ws;                         // max_z x 128
    float* t2  = t1 + (long)max_z * EDGE_DIM;          // max_z x 128
    float* w3c = t2 + (long)max_z * EDGE_DIM;          // 16 x 128
    float* out = (float*)d_out;

    precompute_node_tables<<<max_z, EDGE_DIM, 0, stream>>>(embed_table, edge_w,
                                                           edge_b, t1, t2);
    precompute_rbf_mat<<<N_RADIAL, EDGE_DIM, 0, stream>>>(rbf_w, edge_w, w3c);

    const int nchunks = (n_edges + CHUNK - 1) / CHUNK;
    int grid = nchunks < 2048 ? nchunks : 2048;
    edge_embed_kernel<<<grid, 256, 0, stream>>>(z, rbf, idx_i, idx_j,
                                                t1, t2, w3c, out, n_edges);
}

// Round 3
// 143.014 us; speedup vs baseline: 1.8072x; 1.2767x over previous
//
#include <hip/hip_runtime.h>
#include <hip/hip_fp16.h>
#include <math.h>

#define NODE_DIM 128
#define EDGE_DIM 128
#define N_RADIAL 16
#define MAXZ     100
#define CHUNK    128          // edges per chunk
#define BLOCK    512          // threads per block (8 waves)

// ---------------------------------------------------------------------------
// Precompute: t1[r][d] = sum_k embed[r][k]*edge_w[k][d] + edge_b[d]   (fp16)
//             t2[r][d] = sum_k embed[r][k]*edge_w[128+k][d]           (fp16)
// Stored contiguously: tH[0..MAXZ*128) = t1, tH[MAXZ*128 ..) = t2.
// ---------------------------------------------------------------------------
__global__ void precompute_node_tables(const float* __restrict__ embed_table,
                                       const float* __restrict__ edge_w,
                                       const float* __restrict__ edge_b,
                                       __half* __restrict__ tH) {
    const int r = blockIdx.x;
    const int d = threadIdx.x;
    float s1 = edge_b[d];
    float s2 = 0.0f;
    const float* er = embed_table + (long)r * NODE_DIM;
#pragma unroll 8
    for (int k = 0; k < NODE_DIM; ++k) {
        const float e = er[k];
        s1 += e * edge_w[(long)k * EDGE_DIM + d];
        s2 += e * edge_w[(long)(NODE_DIM + k) * EDGE_DIM + d];
    }
    tH[(long)r * EDGE_DIM + d]          = __float2half(s1);
    tH[(long)(MAXZ + r) * EDGE_DIM + d] = __float2half(s2);
}

// ---------------------------------------------------------------------------
// Precompute: w3c[r][d] = sum_k rbf_w[r][k] * edge_w[256+k][d]   (16x128 fp32)
// ---------------------------------------------------------------------------
__global__ void precompute_rbf_mat(const float* __restrict__ rbf_w,
                                   const float* __restrict__ edge_w,
                                   float* __restrict__ w3c) {
    const int r = blockIdx.x;   // 0..15
    const int d = threadIdx.x;  // 0..127
    float s = 0.0f;
    const float* rr = rbf_w + (long)r * EDGE_DIM;
#pragma unroll 8
    for (int k = 0; k < EDGE_DIM; ++k)
        s += rr[k] * edge_w[(long)(2 * NODE_DIM + k) * EDGE_DIM + d];
    w3c[(long)r * EDGE_DIM + d] = s;
}

// ---------------------------------------------------------------------------
// Main kernel: fp16 t1/t2 tables resident in LDS; double-buffered,
// register-pipelined staging of rbf + resolved z indices; one barrier/chunk.
// ---------------------------------------------------------------------------
__global__ void __launch_bounds__(BLOCK, 4) edge_embed_kernel(
        const int*    __restrict__ z,
        const float*  __restrict__ rbf,
        const int*    __restrict__ idx_i,
        const int*    __restrict__ idx_j,
        const __half* __restrict__ tH,
        const float*  __restrict__ w3c,
        float* __restrict__ out,
        int n_edges, int nch) {
    __shared__ __half sTab[2 * MAXZ * EDGE_DIM];       // 51200 B
    __shared__ float  sRbf[2][CHUNK * N_RADIAL];       // 16384 B
    __shared__ int    sZj[2][CHUNK];                   // 1024 B
    __shared__ int    sZi[2][CHUNK];                   // 1024 B

    const int tid  = threadIdx.x;
    const int sub  = tid & 31;     // float4 column of the 128-wide row
    const int grp  = tid >> 5;     // 0..15: which edge-group
    const int role = tid >> 7;     // 0: zj stager, 1: zi stager, 2-3: none
    const int sl   = tid & 127;

    // this lane's 16x4 slice of w3c -> 64 VGPRs
    float4 w[N_RADIAL];
#pragma unroll
    for (int r = 0; r < N_RADIAL; ++r)
        w[r] = *reinterpret_cast<const float4*>(&w3c[r * EDGE_DIM + (sub << 2)]);

    // cooperative copy of both tables into LDS (3200 uint4 = 51.2 KB)
    {
        const uint4* src = reinterpret_cast<const uint4*>(tH);
        uint4*       dst = reinterpret_cast<uint4*>(sTab);
        for (int i = tid; i < (2 * MAXZ * EDGE_DIM) / 8; i += BLOCK)
            dst[i] = src[i];
    }

    const int bid = blockIdx.x;
    const int nb  = gridDim.x;
    const int clo = (int)(((long)bid * nch) / nb);
    const int chi = (int)(((long)(bid + 1) * nch) / nb);
    if (clo >= chi) return;   // uniform per block

    const int* ip = (role == 0) ? idx_j : idx_i;
    const long nfl = (long)n_edges * N_RADIAL;

    int v = 0;
    // ---- prologue: stage chunk clo into buffer 0; preload idx for clo+1 ----
    {
        int zv = 0;
        if (role < 2) {
            const int e  = clo * CHUNK + sl;
            v  = ip[e < n_edges ? e : n_edges - 1];
            zv = z[v];
        }
        float4 rv;
        const long f4 = (long)clo * BLOCK + tid;
        if (f4 * 4 < nfl)
            rv = *(reinterpret_cast<const float4*>(rbf) + f4);
        else
            rv = make_float4(0.f, 0.f, 0.f, 0.f);
        reinterpret_cast<float4*>(&sRbf[0][0])[tid] = rv;
        if (role == 0)      sZj[0][sl] = zv;
        else if (role == 1) sZi[0][sl] = zv;
        if (clo + 1 < chi && role < 2) {
            const int e2 = (clo + 1) * CHUNK + sl;
            v = ip[e2 < n_edges ? e2 : n_edges - 1];
        }
    }
    __syncthreads();

    for (int c = clo; c < chi; ++c) {
        const int  par  = (c - clo) & 1;
        const bool has1 = (c + 1) < chi;

        // ---- issue next-chunk loads (held in regs until after compute) ----
        int zn = 0;
        float4 rn = make_float4(0.f, 0.f, 0.f, 0.f);
        if (has1) {
            if (role < 2) zn = z[v];
            const long f4 = (long)(c + 1) * BLOCK + tid;
            if (f4 * 4 < nfl)
                rn = *(reinterpret_cast<const float4*>(rbf) + f4);
        }
        if (c + 2 < chi && role < 2) {
            const int e2 = (c + 2) * CHUNK + sl;
            v = ip[e2 < n_edges ? e2 : n_edges - 1];
        }

        // ---- compute chunk c from buffers[par] ----
        const int ebase = c * CHUNK;
#pragma unroll
        for (int s = 0; s < 8; ++s) {
            const int el = (s << 4) | grp;
            const int e  = ebase + el;
            const int zj = sZj[par][el];
            const int zi = sZi[par][el];

            const uint2 uj = *reinterpret_cast<const uint2*>(
                &sTab[zj * EDGE_DIM + (sub << 2)]);
            const uint2 ui = *reinterpret_cast<const uint2*>(
                &sTab[(MAXZ + zi) * EDGE_DIM + (sub << 2)]);
            const float2 aj0 = __half22float2(*reinterpret_cast<const __half2*>(&uj.x));
            const float2 aj1 = __half22float2(*reinterpret_cast<const __half2*>(&uj.y));
            const float2 ai0 = __half22float2(*reinterpret_cast<const __half2*>(&ui.x));
            const float2 ai1 = __half22float2(*reinterpret_cast<const __half2*>(&ui.y));

            float4 acc;
            acc.x = aj0.x + ai0.x;
            acc.y = aj0.y + ai0.y;
            acc.z = aj1.x + ai1.x;
            acc.w = aj1.y + ai1.y;

            const float4* rb =
                reinterpret_cast<const float4*>(&sRbf[par][el * N_RADIAL]);
#pragma unroll
            for (int q = 0; q < 4; ++q) {
                const float4 rq = rb[q];
                acc.x += rq.x * w[q * 4 + 0].x;
                acc.y += rq.x * w[q * 4 + 0].y;
                acc.z += rq.x * w[q * 4 + 0].z;
                acc.w += rq.x * w[q * 4 + 0].w;

                acc.x += rq.y * w[q * 4 + 1].x;
                acc.y += rq.y * w[q * 4 + 1].y;
                acc.z += rq.y * w[q * 4 + 1].z;
                acc.w += rq.y * w[q * 4 + 1].w;

                acc.x += rq.z * w[q * 4 + 2].x;
                acc.y += rq.z * w[q * 4 + 2].y;
                acc.z += rq.z * w[q * 4 + 2].z;
                acc.w += rq.z * w[q * 4 + 2].w;

                acc.x += rq.w * w[q * 4 + 3].x;
                acc.y += rq.w * w[q * 4 + 3].y;
                acc.z += rq.w * w[q * 4 + 3].z;
                acc.w += rq.w * w[q * 4 + 3].w;
            }

            float4 o;
            o.x = acc.x / (1.0f + __expf(-acc.x));
            o.y = acc.y / (1.0f + __expf(-acc.y));
            o.z = acc.z / (1.0f + __expf(-acc.z));
            o.w = acc.w / (1.0f + __expf(-acc.w));

            if (e < n_edges)
                *reinterpret_cast<float4*>(
                    &out[(size_t)e * EDGE_DIM + (sub << 2)]) = o;
        }

        // ---- write staged next-chunk data into the other buffer ----
        if (has1) {
            const int pn = par ^ 1;
            reinterpret_cast<float4*>(&sRbf[pn][0])[tid] = rn;
            if (role == 0)      sZj[pn][sl] = zn;
            else if (role == 1) sZi[pn][sl] = zn;
        }
        __syncthreads();
    }
}

extern "C" void kernel_launch(void* const* d_in, const int* in_sizes, int n_in,
                              void* d_out, int out_size, void* d_ws, size_t ws_size,
                              hipStream_t stream) {
    const int*   zp          = (const int*)  d_in[0];
    const float* rbf         = (const float*)d_in[1];
    const int*   idx_i       = (const int*)  d_in[2];
    const int*   idx_j       = (const int*)  d_in[3];
    const float* embed_table = (const float*)d_in[4];
    const float* rbf_w       = (const float*)d_in[5];
    const float* edge_w      = (const float*)d_in[6];
    const float* edge_b      = (const float*)d_in[7];

    int max_z = in_sizes[4] / NODE_DIM;           // 100
    if (max_z > MAXZ) max_z = MAXZ;
    const int n_edges = in_sizes[2];              // 800000

    __half* tH  = (__half*)d_ws;                               // 2*MAXZ*128 fp16
    float*  w3c = (float*)((char*)d_ws + 2 * MAXZ * EDGE_DIM * sizeof(__half));
    float*  out = (float*)d_out;

    precompute_node_tables<<<max_z, EDGE_DIM, 0, stream>>>(embed_table, edge_w,
                                                           edge_b, tH);
    precompute_rbf_mat<<<N_RADIAL, EDGE_DIM, 0, stream>>>(rbf_w, edge_w, w3c);

    const int nch = (n_edges + CHUNK - 1) / CHUNK;   // 6250
    int grid = nch < 512 ? nch : 512;                // 2 blocks/CU persistent
    edge_embed_kernel<<<grid, BLOCK, 0, stream>>>(zp, rbf, idx_i, idx_j,
                                                  tH, w3c, out, n_edges, nch);
}